// Round 10
// baseline (3697.667 us; speedup 1.0000x reference)
//
#include <hip/hip_runtime.h>
#include <math.h>
#include <stdint.h>

#define NIMG 16
#define A_TOTAL 8732
#define NCLS 80
#define TL_CLS 81
#define CANVASF 300.0f
#define SCORE_THR 0.01f
#define IOU_THRF 0.45f
#define KCAND 400
#define KOUT 200
#define CAND_CAP 4096
#define NBIN 65536

typedef double d4 __attribute__((ext_vector_type(4)));

__device__ __forceinline__ float clampf(float v, float lo, float hi) {
    return fminf(fmaxf(v, lo), hi);
}

// ---------------------------------------------------------------------------
// Conv: LDS-free, barrier-free f64-MFMA waves (round-4/9 structure).
// Round-10 single conv variable: prefetch depth 2 -> 3 at
// __launch_bounds__(256,3): reg cap 170 (64 AGPR + ~75 VGPR, NO spill —
// r7's depth-4 failed purely on spill at the (256,4) 128-reg cap).
// Static occupancy 3 waves/SIMD = 37.5% == measured time-avg at depth 2.
// Group order unchanged (KBg % 3 == 0 at every level) -> bit-identical.
//  - r-major k-order, CN=4, m-fastest tiles, cost-balanced XCD eighths,
//    reg heads folded as extra m rows (all measured-good, kept).
// ---------------------------------------------------------------------------
struct ConvJobs {
    const float* feat[6];
    const float* wgtT[6];
    const float* biasC[6];
    const float* biasR[6];
    float* outc;
    float* outr;
    int Cin[6], lgC[6], Hd[6], Mtot[6], Mcls[6], Mp[6], an[6], off[6];
    int mW[6], jobTiles[6];
    int cum[8][7];   // cum[x][j] = rank of xcd-x blocks before job j; [6]=total
    int cs[8][6];    // chunk start (block index within job) for xcd x
};

struct TransJobs {
    const float* srcC[6];
    const float* srcR[6];
    float* dst[6];
    int Cin[6], K[6], Mcls[6], Mtot[6], Mp[6], mT[6], start[6];
    int total;
};

// ---- coalesced weight transpose: 32x32 tiles through LDS.
// src row m: [ci][ky][kx] -> offset ci*9+r. dst[k'*Mp+m], k' = r*Cin+ci.
// rows [0,Mcls) from cls weights, [Mcls,Mtot) from reg weights, pad to Mp.
__global__ __launch_bounds__(256) void transpose_wgt(TransJobs tj)
{
    __shared__ float lds[32][33];
    int bid = (int)blockIdx.x;
    int L = 0;
    while (L + 1 < 6 && bid >= tj.start[L + 1]) L++;
    int rel = bid - tj.start[L];
    int mTi = rel % tj.mT[L];
    int kTi = rel / tj.mT[L];
    int m0 = mTi * 32, k0 = kTi * 32;
    const int K = tj.K[L];
    const int tid = threadIdx.x;

    // read: 32 m-rows x 32 k, float4 along k (contiguous in src)
    {
        int ml = tid >> 3;
        int kq = (tid & 7) << 2;
        int m = m0 + ml;
        float4 v = make_float4(0.f, 0.f, 0.f, 0.f);
        if (m < tj.Mcls[L])
            v = *(const float4*)(tj.srcC[L] + (size_t)m * K + k0 + kq);
        else if (m < tj.Mtot[L])
            v = *(const float4*)(tj.srcR[L] + (size_t)(m - tj.Mcls[L]) * K + k0 + kq);
        lds[kq + 0][ml] = v.x;
        lds[kq + 1][ml] = v.y;
        lds[kq + 2][ml] = v.z;
        lds[kq + 3][ml] = v.w;
    }
    __syncthreads();
    // write: 32 k'-rows x 32 m, float4 along m (contiguous in dst)
    {
        int kk = tid >> 3;
        int mq = (tid & 7) << 2;
        int k = k0 + kk;
        int ci = k / 9;
        int r = k - ci * 9;
        int kp = r * tj.Cin[L] + ci;
        float4 w;
        w.x = lds[kk][mq + 0];
        w.y = lds[kk][mq + 1];
        w.z = lds[kk][mq + 2];
        w.w = lds[kk][mq + 3];
        *(float4*)(tj.dst[L] + (size_t)kp * tj.Mp[L] + m0 + mq) = w;
    }
}

// ---- per-wave conv tile: 32m x 64n, f64 MFMA, no LDS, no barriers ----
__device__ __forceinline__ void conv_wave(
    const float* __restrict__ feat, const float* __restrict__ wgtT,
    const float* __restrict__ biasC, const float* __restrict__ biasR,
    float* __restrict__ outc, float* __restrict__ outr,
    int Cin, int lgC, int Hd, int Mtot, int Mcls, int Mp, int an, int lvl_off,
    int n0, int m0)
{
    const int K = Cin * 9;
    const int HW = Hd * Hd;
    const int N = NIMG * HW;
    const int CHW = Cin * HW;
    const int lane = threadIdx.x & 63;
    const int lm = lane & 15;
    const int lk = lane >> 4;

    // layout self-calibration (proven): recover (row, col) per acc slot
    int rowIdx[4], colIdx[4];
    {
        d4 z = (d4){0.0, 0.0, 0.0, 0.0};
        d4 pr = __builtin_amdgcn_mfma_f64_16x16x4f64((double)lm, 1.0, z, 0, 0, 0);
        d4 pc = __builtin_amdgcn_mfma_f64_16x16x4f64(1.0, (double)lm, z, 0, 0, 0);
#pragma unroll
        for (int i = 0; i < 4; i++) {
            rowIdx[i] = (int)(pr[i] * 0.25 + 0.5);
            colIdx[i] = (int)(pc[i] * 0.25 + 0.5);
        }
    }

    const int gPerR = Cin >> 2;     // k-groups per kernel tap (power of 2)
    const int KBg = K >> 2;         // total k-groups (divisible by 3: 1152/2304/576)

    int voffA = lk * Mp + m0 + lm;
    int voffB[4];
    float maskc[4];
    float bufA[3][2], bufB[3][4], bufM[3][4];

    d4 acc[2][4];
#pragma unroll
    for (int a = 0; a < 2; a++)
#pragma unroll
        for (int c = 0; c < 4; c++) acc[a][c] = (d4){0.0, 0.0, 0.0, 0.0};

    // recompute per-lane B offsets/masks at a tap boundary (9 times total)
    auto newR = [&](int r) {
        int ky = (r * 171) >> 9;    // r/3 for r<9
        int kx = r - 3 * ky;
#pragma unroll
        for (int c = 0; c < 4; c++) {
            int ng = n0 + lm + 16 * c;
            bool nv = ng < N;
            int bimg = 0, p = 0;
            if (nv) { bimg = ng / HW; p = ng - bimg * HW; }
            int y0 = p / Hd;
            int x0 = p - y0 * Hd;
            int yy = y0 + ky - 1;
            int xx = x0 + kx - 1;
            bool v = nv && (yy >= 0) && (yy < Hd) && (xx >= 0) && (xx < Hd);
            maskc[c] = v ? 1.0f : 0.0f;
            voffB[c] = bimg * CHW + lk * HW + (v ? (yy * Hd + xx) : 0);
        }
    };

    auto loadG = [&](int g, int slot) {
        if ((g & (gPerR - 1)) == 0) newR(g >> (lgC - 2));
#pragma unroll
        for (int c = 0; c < 4; c++) {
            bufB[slot][c] = feat[voffB[c]];
            bufM[slot][c] = maskc[c];
            voffB[c] += 4 * HW;
        }
        bufA[slot][0] = wgtT[voffA];
        bufA[slot][1] = wgtT[voffA + 16];
        voffA += 4 * Mp;
    };

    // 3-deep software pipeline: slots 0..2 in flight (group order unchanged)
    loadG(0, 0);
    loadG(1, 1);
    loadG(2, 2);
    for (int g = 0; g < KBg; g += 3) {
#pragma unroll
        for (int u = 0; u < 3; u++) {
            double a0 = (double)bufA[u][0];
            double a1 = (double)bufA[u][1];
            double b0 = (double)(bufB[u][0] * bufM[u][0]);
            double b1 = (double)(bufB[u][1] * bufM[u][1]);
            double b2 = (double)(bufB[u][2] * bufM[u][2]);
            double b3 = (double)(bufB[u][3] * bufM[u][3]);
            if (g + 3 + u < KBg) loadG(g + 3 + u, u);
            acc[0][0] = __builtin_amdgcn_mfma_f64_16x16x4f64(a0, b0, acc[0][0], 0, 0, 0);
            acc[1][0] = __builtin_amdgcn_mfma_f64_16x16x4f64(a1, b0, acc[1][0], 0, 0, 0);
            acc[0][1] = __builtin_amdgcn_mfma_f64_16x16x4f64(a0, b1, acc[0][1], 0, 0, 0);
            acc[1][1] = __builtin_amdgcn_mfma_f64_16x16x4f64(a1, b1, acc[1][1], 0, 0, 0);
            acc[0][2] = __builtin_amdgcn_mfma_f64_16x16x4f64(a0, b2, acc[0][2], 0, 0, 0);
            acc[1][2] = __builtin_amdgcn_mfma_f64_16x16x4f64(a1, b2, acc[1][2], 0, 0, 0);
            acc[0][3] = __builtin_amdgcn_mfma_f64_16x16x4f64(a0, b3, acc[0][3], 0, 0, 0);
            acc[1][3] = __builtin_amdgcn_mfma_f64_16x16x4f64(a1, b3, acc[1][3], 0, 0, 0);
        }
    }

    // epilogue: probe-derived (row, col) per slot; route cls / reg rows
#pragma unroll
    for (int mi2 = 0; mi2 < 2; mi2++)
#pragma unroll
    for (int c = 0; c < 4; c++)
#pragma unroll
    for (int i = 0; i < 4; i++) {
        int mg = m0 + mi2 * 16 + rowIdx[i];
        int ng2 = n0 + c * 16 + colIdx[i];
        if (mg >= Mtot || ng2 >= N) continue;
        int b = ng2 / HW;
        int p = ng2 - b * HW;
        double val = acc[mi2][c][i];
        if (mg < Mcls) {
            int aidx = mg / TL_CLS;
            int t = mg - aidx * TL_CLS;
            int row = lvl_off + p * an + aidx;
            outc[((size_t)b * A_TOTAL + row) * TL_CLS + t] = (float)(val + (double)biasC[mg]);
        } else {
            int rm = mg - Mcls;
            int aidx = rm >> 2;
            int t = rm & 3;
            int row = lvl_off + p * an + aidx;
            outr[((size_t)b * A_TOTAL + row) * 4 + t] = (float)(val + (double)biasR[rm]);
        }
    }
}

__global__ __launch_bounds__(256, 3) void fused_conv(ConvJobs J)
{
    // cost-balanced XCD chunking: XCD x (= bid&7 under HW round-robin
    // dispatch) runs contiguous sub-chunk x of EVERY job, in job order.
    int bid = (int)blockIdx.x;
    int x = bid & 7;
    int r = bid >> 3;                 // rank within this XCD
    if (r >= J.cum[x][6]) return;     // padded tail
    int j = 0;
    while (j + 1 < 6 && r >= J.cum[x][j + 1]) j++;
    int blkInJob = J.cs[x][j] + (r - J.cum[x][j]);

    int wave = threadIdx.x >> 6;
    int tile = blkInJob * 4 + wave;
    if (tile >= J.jobTiles[j]) return;
    int mt = tile % J.mW[j];          // m-FASTEST: adjacent tiles share B
    int nt = tile / J.mW[j];

    conv_wave(J.feat[j], J.wgtT[j], J.biasC[j], J.biasR[j], J.outc, J.outr,
              J.Cin[j], J.lgC[j], J.Hd[j], J.Mtot[j], J.Mcls[j], J.Mp[j],
              J.an[j], J.off[j], nt * 64, mt * 32);
}

// ---------------------------------------------------------------------------
// Softmax over 81 classes (f64 internally), drop background class 0.
// Round-10: parallel max/exp (4 threads/row); the f64 SUM stays serial in
// the original c=0..80 order with identical values -> bit-identical scores.
// hist fused in (round-6 win, kept).
// ---------------------------------------------------------------------------
__global__ __launch_bounds__(256) void softmax_kernel(
    const float* __restrict__ cls, float* __restrict__ scr,
    unsigned int* __restrict__ hist, int nrows)
{
    __shared__ double ebuf[64][81];   // 41472 B
    __shared__ double pmax[64][4];
    __shared__ float inv[64];
    const int row0 = blockIdx.x * 64;
    const int tid = threadIdx.x;

    for (int i = tid; i < 64 * 81; i += 256) {
        int r = i / 81;
        int c = i - r * 81;
        int gr = row0 + r;
        ebuf[r][c] = (gr < nrows) ? (double)cls[(size_t)row0 * 81 + i] : 0.0;
    }
    __syncthreads();
    {
        int r = tid >> 2, q = tid & 3;
        double m = -1e30;
        for (int c = q; c < 81; c += 4) m = fmax(m, ebuf[r][c]);
        pmax[r][q] = m;
    }
    __syncthreads();
    {
        int r = tid >> 2, q = tid & 3;
        double md = fmax(fmax(pmax[r][0], pmax[r][1]), fmax(pmax[r][2], pmax[r][3]));
        for (int c = q; c < 81; c += 4) ebuf[r][c] = exp(ebuf[r][c] - md);
    }
    __syncthreads();
    if (tid < 64) {
        double ssum = 0.0;
        for (int c = 0; c < 81; c++) ssum += ebuf[tid][c];   // original order
        inv[tid] = (float)(1.0 / ssum);
    }
    __syncthreads();
    for (int i = tid; i < 64 * 80; i += 256) {
        int r = i / 80;
        int c = i - r * 80;
        int gr = row0 + r;
        if (gr < nrows) {
            float v = (float)ebuf[r][c + 1] * inv[r];
            scr[(size_t)gr * 80 + c] = v;
            if (v > SCORE_THR) {
                int img = gr / A_TOTAL;
                atomicAdd(&hist[img * NBIN + (__float_as_uint(v) >> 16)], 1u);
            }
        }
    }
}

// ---------------------------------------------------------------------------
__global__ void zero_kernel(unsigned int* __restrict__ p, int n)
{
    int i = blockIdx.x * blockDim.x + threadIdx.x;
    if (i < n) p[i] = 0u;
}

// ---------------------------------------------------------------------------
// select: per-thread 64-bin partials + LDS suffix-scan (22 barriers vs 640).
// b0 = first bin (from top) where cumulative count reaches KCAND; 0 if never.
// ---------------------------------------------------------------------------
__global__ __launch_bounds__(1024) void select_kernel(
    const unsigned int* __restrict__ hist, unsigned int* __restrict__ sel)
{
    __shared__ unsigned int ps[1024];
    __shared__ int s_found;
    const int img = blockIdx.x;
    const int tid = threadIdx.x;

    unsigned int p = 0;
    const int base = img * NBIN + tid * 64;
    for (int j = 0; j < 64; j++) p += hist[base + j];
    ps[tid] = p;
    if (tid == 0) s_found = 0;
    __syncthreads();

    // inclusive suffix sum: ps[t] = sum_{t' >= t} p[t']
    for (int off = 1; off < 1024; off <<= 1) {
        unsigned int v = (tid + off < 1024) ? ps[tid + off] : 0u;
        __syncthreads();
        ps[tid] += v;
        __syncthreads();
    }

    unsigned int St = ps[tid];
    unsigned int Sn = (tid < 1023) ? ps[tid + 1] : 0u;
    if (St >= KCAND && (tid == 1023 || Sn < KCAND)) {
        // unique thread: walk its 64 bins from the top
        unsigned int cum = Sn;
        int b0 = 0;
        for (int b = tid * 64 + 63; b >= tid * 64; b--) {
            cum += hist[img * NBIN + b];
            if (cum >= KCAND) { b0 = b; break; }
        }
        sel[img] = (unsigned int)b0;
        s_found = 1;
    }
    __syncthreads();
    if (tid == 0 && !s_found) sel[img] = 0u;
}

// ---------------------------------------------------------------------------
__global__ void gather_kernel(const float* __restrict__ scr,
                              const unsigned int* __restrict__ sel,
                              unsigned int* __restrict__ candcnt,
                              uint2* __restrict__ cand)
{
    const int per_img = A_TOTAL * NCLS;
    const size_t total = (size_t)NIMG * per_img;
    for (size_t i = (size_t)blockIdx.x * blockDim.x + threadIdx.x; i < total;
         i += (size_t)gridDim.x * blockDim.x) {
        float v = scr[i];
        if (v > SCORE_THR) {
            int img = (int)(i / per_img);
            unsigned int u = __float_as_uint(v);
            if ((u >> 16) >= sel[img]) {
                unsigned int pos = atomicAdd(&candcnt[img], 1u);
                if (pos < CAND_CAP) {
                    unsigned int ridx = (unsigned int)(i - (size_t)img * per_img);
                    cand[(size_t)img * CAND_CAP + pos] = make_uint2(u, ridx);
                }
            }
        }
    }
}

// ---------------------------------------------------------------------------
__global__ __launch_bounds__(1024) void nms_kernel(
    const uint2* __restrict__ cand, const unsigned int* __restrict__ candcnt,
    const float* __restrict__ reg_all, const float* __restrict__ priors,
    float* __restrict__ out)
{
    __shared__ unsigned long long key[CAND_CAP];
    __shared__ float s_sc[KCAND];
    __shared__ float s_bx[KCAND][4];
    __shared__ float s_ob[KCAND][4];
    __shared__ float s_ar[KCAND];
    __shared__ float s_cl[KCAND];
    __shared__ int s_keep[KCAND];
    __shared__ int s_fi[KOUT];

    const int img = blockIdx.x;
    const int tid = threadIdx.x;
    unsigned int craw = candcnt[img];
    const int cnt = (craw > CAND_CAP) ? CAND_CAP : (int)craw;

    for (int i = tid; i < CAND_CAP; i += 1024) {
        unsigned long long kv = 0ull;
        if (i < cnt) {
            uint2 e = cand[(size_t)img * CAND_CAP + i];
            kv = ((unsigned long long)e.x << 32) | (unsigned int)(~e.y);
        }
        key[i] = kv;
    }
    __syncthreads();

    for (int ksz = 2; ksz <= CAND_CAP; ksz <<= 1) {
        for (int jj = ksz >> 1; jj > 0; jj >>= 1) {
            for (int i = tid; i < CAND_CAP; i += 1024) {
                int p = i ^ jj;
                if (p > i) {
                    bool desc = ((i & ksz) == 0);
                    unsigned long long a = key[i];
                    unsigned long long b = key[p];
                    bool sw = desc ? (a < b) : (a > b);
                    if (sw) { key[i] = b; key[p] = a; }
                }
            }
            __syncthreads();
        }
    }

    const float CLIPF = 4.135166556742356f;
    if (tid < KCAND) {
        const int j = tid;
        float s = 0.0f;
        unsigned int idx = 0u;
        if (j < cnt) {
            unsigned long long kv = key[j];
            unsigned int bits = (unsigned int)(kv >> 32);
            idx = ~((unsigned int)kv);
            s = __uint_as_float(bits);
        }
        int anc = (int)(idx / NCLS);
        int cl = (int)(idx - (unsigned int)anc * NCLS) + 1;
        const float* d = reg_all + ((size_t)img * A_TOTAL + anc) * 4;
        const float* pr = priors + (size_t)anc * 4;
        float d0 = d[0], d1 = d[1], d2 = d[2], d3 = d[3];
        float p0 = pr[0], p1 = pr[1], p2 = pr[2], p3 = pr[3];
        float cx = p0 + d0 * 0.1f * p2;
        float cy = p1 + d1 * 0.1f * p3;
        float t2 = fminf(d2 * 0.2f, CLIPF);
        float t3 = fminf(d3 * 0.2f, CLIPF);
        float bw = p2 * (float)exp((double)t2);
        float bh = p3 * (float)exp((double)t3);
        float x1 = clampf(cx - 0.5f * bw, 0.0f, CANVASF);
        float y1 = clampf(cy - 0.5f * bh, 0.0f, CANVASF);
        float x2 = clampf(cx + 0.5f * bw, 0.0f, CANVASF);
        float y2 = clampf(cy + 0.5f * bh, 0.0f, CANVASF);
        bool valid = (s > 0.0f) && (x2 > x1) && (y2 > y1);
        s = valid ? s : 0.0f;
        float off = (float)cl * (CANVASF + 1.0f);
        float ox1 = x1 + off, oy1 = y1 + off, ox2 = x2 + off, oy2 = y2 + off;
        s_sc[j] = s;
        s_cl[j] = (float)cl;
        s_keep[j] = valid ? 1 : 0;
        s_bx[j][0] = x1; s_bx[j][1] = y1; s_bx[j][2] = x2; s_bx[j][3] = y2;
        s_ob[j][0] = ox1; s_ob[j][1] = oy1; s_ob[j][2] = ox2; s_ob[j][3] = oy2;
        s_ar[j] = (ox2 - ox1) * (oy2 - oy1);
    }
    __syncthreads();

    for (int i = 0; i < KCAND; i++) {
        int ki = s_keep[i];
        if (ki && tid < KCAND && tid > i) {
            float lx = fmaxf(s_ob[i][0], s_ob[tid][0]);
            float ly = fmaxf(s_ob[i][1], s_ob[tid][1]);
            float rx = fminf(s_ob[i][2], s_ob[tid][2]);
            float ry = fminf(s_ob[i][3], s_ob[tid][3]);
            float iw = fmaxf(rx - lx, 0.0f);
            float ih = fmaxf(ry - ly, 0.0f);
            float inter = iw * ih;
            float iou = inter / (s_ar[i] + s_ar[tid] - inter + 1e-9f);
            if (iou > IOU_THRF) s_keep[tid] = 0;
        }
        __syncthreads();
    }

    if (tid == 0) {
        int pos = 0;
        for (int j = 0; j < KCAND && pos < KOUT; j++)
            if (s_keep[j]) s_fi[pos++] = j;
        for (int j = 0; j < KCAND && pos < KOUT; j++)
            if (!s_keep[j]) s_fi[pos++] = j;
    }
    __syncthreads();

    if (tid < KOUT) {
        int j = s_fi[tid];
        float fs = s_keep[j] ? s_sc[j] : 0.0f;
        size_t o = (size_t)img * KOUT + tid;
        out[o * 4 + 0] = s_bx[j][0];
        out[o * 4 + 1] = s_bx[j][1];
        out[o * 4 + 2] = s_bx[j][2];
        out[o * 4 + 3] = s_bx[j][3];
        out[(size_t)NIMG * KOUT * 4 + o] = fs;
        out[(size_t)NIMG * KOUT * 5 + o] = (fs > 0.0f) ? s_cl[j] : 0.0f;
    }
}

// ---------------------------------------------------------------------------
extern "C" void kernel_launch(void* const* d_in, const int* in_sizes, int n_in,
                              void* d_out, int out_size, void* d_ws, size_t ws_size,
                              hipStream_t stream)
{
    static const int Cin_[6] = {512, 1024, 512, 256, 256, 256};
    static const int lgC_[6] = {9, 10, 9, 8, 8, 8};
    static const int HW_[6]  = {38, 19, 10, 5, 3, 1};
    static const int an_[6]  = {4, 6, 6, 6, 4, 4};
    static const int off_[6] = {0, 5776, 7942, 8542, 8692, 8728};
    // combined (cls 81 + reg 4) transposed weights: M = an*85, Mp mult of 32
    static const int Mp_[6]  = {352, 512, 512, 512, 352, 352};
    // float offsets inside scr region (L4 goes to hist region instead)
    static const size_t wOffF_[6] = {0, 1622016, 6340608, 8699904, 0, 9879552};

    char* ws = (char*)d_ws;
    const size_t OFF_CLS  = 0;
    const size_t OFF_SCR  = 45266688;
    const size_t OFF_REG  = 89974528;
    const size_t OFF_HIST = 92209920;
    const size_t OFF_CCNT = 96404224;
    const size_t OFF_SEL  = 96404288;
    const size_t OFF_CAND = 96404352;

    float* cls_all = (float*)(ws + OFF_CLS);
    float* scr     = (float*)(ws + OFF_SCR);
    float* reg_all = (float*)(ws + OFF_REG);
    unsigned int* hist    = (unsigned int*)(ws + OFF_HIST);
    unsigned int* candcnt = (unsigned int*)(ws + OFF_CCNT);
    unsigned int* sel     = (unsigned int*)(ws + OFF_SEL);
    uint2* cand           = (uint2*)(ws + OFF_CAND);

    float* wT = scr;             // 42.8 MB of 44.7 MB scr region (L0-3, L5)
    float* hT = (float*)hist;    // 3.24 MB of 4.19 MB hist region (L4)

    // ---- combined weight transpose (cls + reg rows), before conv ----
    {
        TransJobs tj;
        int ts = 0;
        for (int L = 0; L < 6; L++) {
            tj.srcC[L] = (const float*)d_in[L * 5 + 1];
            tj.srcR[L] = (const float*)d_in[L * 5 + 3];
            tj.dst[L] = (L == 4) ? hT : (wT + wOffF_[L]);
            tj.Cin[L] = Cin_[L];
            tj.K[L] = Cin_[L] * 9;
            tj.Mcls[L] = an_[L] * TL_CLS;
            tj.Mtot[L] = an_[L] * 85;
            tj.Mp[L] = Mp_[L];
            tj.mT[L] = Mp_[L] / 32;
            tj.start[L] = ts;
            ts += (Mp_[L] / 32) * (Cin_[L] * 9 / 32);
        }
        tj.total = ts;
        transpose_wgt<<<ts, 256, 0, stream>>>(tj);
    }

    // ---- fused conv: XCD-chunked m-fastest wave tiles, CN=4 everywhere ----
    ConvJobs jobs;
    static const int ord_lvl[6] = {1, 0, 2, 3, 4, 5};
    int Bj[6];
    for (int q = 0; q < 6; q++) {
        int L = ord_lvl[q];
        int an = an_[L];
        jobs.feat[q]  = (const float*)d_in[L * 5 + 0];
        jobs.wgtT[q]  = (L == 4) ? hT : (wT + wOffF_[L]);
        jobs.biasC[q] = (const float*)d_in[L * 5 + 2];
        jobs.biasR[q] = (const float*)d_in[L * 5 + 4];
        jobs.Cin[q]   = Cin_[L];
        jobs.lgC[q]   = lgC_[L];
        jobs.Hd[q]    = HW_[L];
        jobs.Mcls[q]  = an * TL_CLS;
        jobs.Mtot[q]  = an * 85;
        jobs.Mp[q]    = Mp_[L];
        jobs.an[q]    = an;
        jobs.off[q]   = off_[L];
        int N = NIMG * HW_[L] * HW_[L];
        int nT = (N + 63) / 64;
        int mW = (jobs.Mtot[q] + 31) / 32;
        jobs.mW[q] = mW;
        jobs.jobTiles[q] = nT * mW;
        Bj[q] = (nT * mW + 3) / 4;
    }
    int maxT = 0;
    for (int x = 0; x < 8; x++) {
        int acc = 0;
        for (int q = 0; q < 6; q++) {
            int s = (int)(((long long)x * Bj[q]) / 8);
            int e = (int)(((long long)(x + 1) * Bj[q]) / 8);
            jobs.cs[x][q] = s;
            jobs.cum[x][q] = acc;
            acc += e - s;
        }
        jobs.cum[x][6] = acc;
        if (acc > maxT) maxT = acc;
    }
    jobs.outc = cls_all;
    jobs.outr = reg_all;

    fused_conv<<<8 * maxT, 256, 0, stream>>>(jobs);

    // zero hist/candcnt/sel AFTER conv (L4 weights live in the hist region)
    {
        int nz = NIMG * NBIN + 16 + 16;
        zero_kernel<<<(nz + 255) / 256, 256, 0, stream>>>(hist, nz);
    }

    softmax_kernel<<<(NIMG * A_TOTAL + 63) / 64, 256, 0, stream>>>(
        cls_all, scr, hist, NIMG * A_TOTAL);
    select_kernel<<<NIMG, 1024, 0, stream>>>(hist, sel);
    gather_kernel<<<2048, 256, 0, stream>>>(scr, sel, candcnt, cand);
    nms_kernel<<<NIMG, 1024, 0, stream>>>(cand, candcnt, reg_all,
                                          (const float*)d_in[30], (float*)d_out);
}

// Round 11
// 3577.813 us; speedup vs baseline: 1.0335x; 1.0335x over previous
//
#include <hip/hip_runtime.h>
#include <math.h>
#include <stdint.h>

#define NIMG 16
#define A_TOTAL 8732
#define NCLS 80
#define TL_CLS 81
#define CANVASF 300.0f
#define SCORE_THR 0.01f
#define IOU_THRF 0.45f
#define KCAND 400
#define KOUT 200
#define CAND_CAP 4096
#define NBIN 65536

typedef double d4 __attribute__((ext_vector_type(4)));

__device__ __forceinline__ float clampf(float v, float lo, float hi) {
    return fminf(fmaxf(v, lo), hi);
}

// ---------------------------------------------------------------------------
// Conv: LDS-free, barrier-free f64-MFMA waves — ROUND-9 STRUCTURE VERBATIM
// (best measured: total 3582us, conv 2920us, MfmaUtil 66%, no spill)
// plus ONE variable: per-wave phase stagger (w x s_sleep(3) at entry).
// Convoy theory: waves run identical-cadence phases in lockstep, so MFMA
// bursts collide -> pipe util pinned at single-wave duty 512/(512+264)=66%
// (matches r9 depth-2/4-wave AND r10 depth-3/3-wave exactly). The stagger
// offsets wave phases by ~192cy each across the ~776cy group period.
// Numerics: zero change (sleep only) -> bit-identical outputs.
// ---------------------------------------------------------------------------
struct ConvJobs {
    const float* feat[6];
    const float* wgtT[6];
    const float* biasC[6];
    const float* biasR[6];
    float* outc;
    float* outr;
    int Cin[6], lgC[6], Hd[6], Mtot[6], Mcls[6], Mp[6], an[6], off[6];
    int mW[6], jobTiles[6];
    int cum[8][7];   // cum[x][j] = rank of xcd-x blocks before job j; [6]=total
    int cs[8][6];    // chunk start (block index within job) for xcd x
};

struct TransJobs {
    const float* srcC[6];
    const float* srcR[6];
    float* dst[6];
    int Cin[6], K[6], Mcls[6], Mtot[6], Mp[6], mT[6], start[6];
    int total;
};

// ---- coalesced weight transpose: 32x32 tiles through LDS.
// src row m: [ci][ky][kx] -> offset ci*9+r. dst[k'*Mp+m], k' = r*Cin+ci.
// rows [0,Mcls) from cls weights, [Mcls,Mtot) from reg weights, pad to Mp.
__global__ __launch_bounds__(256) void transpose_wgt(TransJobs tj)
{
    __shared__ float lds[32][33];
    int bid = (int)blockIdx.x;
    int L = 0;
    while (L + 1 < 6 && bid >= tj.start[L + 1]) L++;
    int rel = bid - tj.start[L];
    int mTi = rel % tj.mT[L];
    int kTi = rel / tj.mT[L];
    int m0 = mTi * 32, k0 = kTi * 32;
    const int K = tj.K[L];
    const int tid = threadIdx.x;

    // read: 32 m-rows x 32 k, float4 along k (contiguous in src)
    {
        int ml = tid >> 3;
        int kq = (tid & 7) << 2;
        int m = m0 + ml;
        float4 v = make_float4(0.f, 0.f, 0.f, 0.f);
        if (m < tj.Mcls[L])
            v = *(const float4*)(tj.srcC[L] + (size_t)m * K + k0 + kq);
        else if (m < tj.Mtot[L])
            v = *(const float4*)(tj.srcR[L] + (size_t)(m - tj.Mcls[L]) * K + k0 + kq);
        lds[kq + 0][ml] = v.x;
        lds[kq + 1][ml] = v.y;
        lds[kq + 2][ml] = v.z;
        lds[kq + 3][ml] = v.w;
    }
    __syncthreads();
    // write: 32 k'-rows x 32 m, float4 along m (contiguous in dst)
    {
        int kk = tid >> 3;
        int mq = (tid & 7) << 2;
        int k = k0 + kk;
        int ci = k / 9;
        int r = k - ci * 9;
        int kp = r * tj.Cin[L] + ci;
        float4 w;
        w.x = lds[kk][mq + 0];
        w.y = lds[kk][mq + 1];
        w.z = lds[kk][mq + 2];
        w.w = lds[kk][mq + 3];
        *(float4*)(tj.dst[L] + (size_t)kp * tj.Mp[L] + m0 + mq) = w;
    }
}

// ---- per-wave conv tile: 32m x 64n, f64 MFMA, no LDS, no barriers ----
__device__ __forceinline__ void conv_wave(
    const float* __restrict__ feat, const float* __restrict__ wgtT,
    const float* __restrict__ biasC, const float* __restrict__ biasR,
    float* __restrict__ outc, float* __restrict__ outr,
    int Cin, int lgC, int Hd, int Mtot, int Mcls, int Mp, int an, int lvl_off,
    int n0, int m0)
{
    const int K = Cin * 9;
    const int HW = Hd * Hd;
    const int N = NIMG * HW;
    const int CHW = Cin * HW;
    const int lane = threadIdx.x & 63;
    const int lm = lane & 15;
    const int lk = lane >> 4;

    // layout self-calibration (proven): recover (row, col) per acc slot
    int rowIdx[4], colIdx[4];
    {
        d4 z = (d4){0.0, 0.0, 0.0, 0.0};
        d4 pr = __builtin_amdgcn_mfma_f64_16x16x4f64((double)lm, 1.0, z, 0, 0, 0);
        d4 pc = __builtin_amdgcn_mfma_f64_16x16x4f64(1.0, (double)lm, z, 0, 0, 0);
#pragma unroll
        for (int i = 0; i < 4; i++) {
            rowIdx[i] = (int)(pr[i] * 0.25 + 0.5);
            colIdx[i] = (int)(pc[i] * 0.25 + 0.5);
        }
    }

    // convoy-breaking phase stagger: wave w starts ~192*w cycles late.
    // Pure delay — no instruction-stream or numeric change.
    {
        int ph = (threadIdx.x >> 6) & 3;
        for (int i = 0; i < ph; i++) __builtin_amdgcn_s_sleep(3);
    }

    const int gPerR = Cin >> 2;     // k-groups per kernel tap (power of 2)
    const int KBg = K >> 2;         // total k-groups (always even)

    int voffA = lk * Mp + m0 + lm;
    int voffB[4];
    float maskc[4];
    float bufA[2][2], bufB[2][4], bufM[2][4];

    d4 acc[2][4];
#pragma unroll
    for (int a = 0; a < 2; a++)
#pragma unroll
        for (int c = 0; c < 4; c++) acc[a][c] = (d4){0.0, 0.0, 0.0, 0.0};

    // recompute per-lane B offsets/masks at a tap boundary (9 times total)
    auto newR = [&](int r) {
        int ky = (r * 171) >> 9;    // r/3 for r<9
        int kx = r - 3 * ky;
#pragma unroll
        for (int c = 0; c < 4; c++) {
            int ng = n0 + lm + 16 * c;
            bool nv = ng < N;
            int bimg = 0, p = 0;
            if (nv) { bimg = ng / HW; p = ng - bimg * HW; }
            int y0 = p / Hd;
            int x0 = p - y0 * Hd;
            int yy = y0 + ky - 1;
            int xx = x0 + kx - 1;
            bool v = nv && (yy >= 0) && (yy < Hd) && (xx >= 0) && (xx < Hd);
            maskc[c] = v ? 1.0f : 0.0f;
            voffB[c] = bimg * CHW + lk * HW + (v ? (yy * Hd + xx) : 0);
        }
    };

    auto loadG = [&](int g, int slot) {
        if ((g & (gPerR - 1)) == 0) newR(g >> (lgC - 2));
#pragma unroll
        for (int c = 0; c < 4; c++) {
            bufB[slot][c] = feat[voffB[c]];
            bufM[slot][c] = maskc[c];
            voffB[c] += 4 * HW;
        }
        bufA[slot][0] = wgtT[voffA];
        bufA[slot][1] = wgtT[voffA + 16];
        voffA += 4 * Mp;
    };

    loadG(0, 0);
    loadG(1, 1);
    for (int g = 0; g < KBg; g += 2) {
        {
            double a0 = (double)bufA[0][0];
            double a1 = (double)bufA[0][1];
            double b0 = (double)(bufB[0][0] * bufM[0][0]);
            double b1 = (double)(bufB[0][1] * bufM[0][1]);
            double b2 = (double)(bufB[0][2] * bufM[0][2]);
            double b3 = (double)(bufB[0][3] * bufM[0][3]);
            if (g + 2 < KBg) loadG(g + 2, 0);
            acc[0][0] = __builtin_amdgcn_mfma_f64_16x16x4f64(a0, b0, acc[0][0], 0, 0, 0);
            acc[1][0] = __builtin_amdgcn_mfma_f64_16x16x4f64(a1, b0, acc[1][0], 0, 0, 0);
            acc[0][1] = __builtin_amdgcn_mfma_f64_16x16x4f64(a0, b1, acc[0][1], 0, 0, 0);
            acc[1][1] = __builtin_amdgcn_mfma_f64_16x16x4f64(a1, b1, acc[1][1], 0, 0, 0);
            acc[0][2] = __builtin_amdgcn_mfma_f64_16x16x4f64(a0, b2, acc[0][2], 0, 0, 0);
            acc[1][2] = __builtin_amdgcn_mfma_f64_16x16x4f64(a1, b2, acc[1][2], 0, 0, 0);
            acc[0][3] = __builtin_amdgcn_mfma_f64_16x16x4f64(a0, b3, acc[0][3], 0, 0, 0);
            acc[1][3] = __builtin_amdgcn_mfma_f64_16x16x4f64(a1, b3, acc[1][3], 0, 0, 0);
        }
        {
            double a0 = (double)bufA[1][0];
            double a1 = (double)bufA[1][1];
            double b0 = (double)(bufB[1][0] * bufM[1][0]);
            double b1 = (double)(bufB[1][1] * bufM[1][1]);
            double b2 = (double)(bufB[1][2] * bufM[1][2]);
            double b3 = (double)(bufB[1][3] * bufM[1][3]);
            if (g + 3 < KBg) loadG(g + 3, 1);
            acc[0][0] = __builtin_amdgcn_mfma_f64_16x16x4f64(a0, b0, acc[0][0], 0, 0, 0);
            acc[1][0] = __builtin_amdgcn_mfma_f64_16x16x4f64(a1, b0, acc[1][0], 0, 0, 0);
            acc[0][1] = __builtin_amdgcn_mfma_f64_16x16x4f64(a0, b1, acc[0][1], 0, 0, 0);
            acc[1][1] = __builtin_amdgcn_mfma_f64_16x16x4f64(a1, b1, acc[1][1], 0, 0, 0);
            acc[0][2] = __builtin_amdgcn_mfma_f64_16x16x4f64(a0, b2, acc[0][2], 0, 0, 0);
            acc[1][2] = __builtin_amdgcn_mfma_f64_16x16x4f64(a1, b2, acc[1][2], 0, 0, 0);
            acc[0][3] = __builtin_amdgcn_mfma_f64_16x16x4f64(a0, b3, acc[0][3], 0, 0, 0);
            acc[1][3] = __builtin_amdgcn_mfma_f64_16x16x4f64(a1, b3, acc[1][3], 0, 0, 0);
        }
    }

    // epilogue: probe-derived (row, col) per slot; route cls / reg rows
#pragma unroll
    for (int mi2 = 0; mi2 < 2; mi2++)
#pragma unroll
    for (int c = 0; c < 4; c++)
#pragma unroll
    for (int i = 0; i < 4; i++) {
        int mg = m0 + mi2 * 16 + rowIdx[i];
        int ng2 = n0 + c * 16 + colIdx[i];
        if (mg >= Mtot || ng2 >= N) continue;
        int b = ng2 / HW;
        int p = ng2 - b * HW;
        double val = acc[mi2][c][i];
        if (mg < Mcls) {
            int aidx = mg / TL_CLS;
            int t = mg - aidx * TL_CLS;
            int row = lvl_off + p * an + aidx;
            outc[((size_t)b * A_TOTAL + row) * TL_CLS + t] = (float)(val + (double)biasC[mg]);
        } else {
            int rm = mg - Mcls;
            int aidx = rm >> 2;
            int t = rm & 3;
            int row = lvl_off + p * an + aidx;
            outr[((size_t)b * A_TOTAL + row) * 4 + t] = (float)(val + (double)biasR[rm]);
        }
    }
}

__global__ __launch_bounds__(256, 4) void fused_conv(ConvJobs J)
{
    // cost-balanced XCD chunking: XCD x (= bid&7 under HW round-robin
    // dispatch) runs contiguous sub-chunk x of EVERY job, in job order.
    int bid = (int)blockIdx.x;
    int x = bid & 7;
    int r = bid >> 3;                 // rank within this XCD
    if (r >= J.cum[x][6]) return;     // padded tail
    int j = 0;
    while (j + 1 < 6 && r >= J.cum[x][j + 1]) j++;
    int blkInJob = J.cs[x][j] + (r - J.cum[x][j]);

    int wave = threadIdx.x >> 6;
    int tile = blkInJob * 4 + wave;
    if (tile >= J.jobTiles[j]) return;
    int mt = tile % J.mW[j];          // m-FASTEST: adjacent tiles share B
    int nt = tile / J.mW[j];

    conv_wave(J.feat[j], J.wgtT[j], J.biasC[j], J.biasR[j], J.outc, J.outr,
              J.Cin[j], J.lgC[j], J.Hd[j], J.Mtot[j], J.Mcls[j], J.Mp[j],
              J.an[j], J.off[j], nt * 64, mt * 32);
}

// ---------------------------------------------------------------------------
// Softmax over 81 classes (f64 internally), drop background class 0.
// ROUND-9 VERSION (round-10's f64-LDS rework regressed ~100us — reverted).
// hist fused in (saves a full 45 MB re-read pass + one launch).
// ---------------------------------------------------------------------------
__global__ __launch_bounds__(256) void softmax_kernel(
    const float* __restrict__ cls, float* __restrict__ scr,
    unsigned int* __restrict__ hist, int nrows)
{
    __shared__ float buf[64 * 81];
    __shared__ float inv[64];
    const int row0 = blockIdx.x * 64;
    const int tid = threadIdx.x;

    for (int i = tid; i < 64 * 81; i += 256) {
        int r = row0 + i / 81;
        buf[i] = (r < nrows) ? cls[(size_t)row0 * 81 + i] : 0.0f;
    }
    __syncthreads();
    if (tid < 64) {
        float m = -1e30f;
        for (int c = 0; c < 81; c++) m = fmaxf(m, buf[tid * 81 + c]);
        double md = (double)m;
        double ssum = 0.0;
        for (int c = 0; c < 81; c++) {
            double e = exp((double)buf[tid * 81 + c] - md);
            buf[tid * 81 + c] = (float)e;
            ssum += e;
        }
        inv[tid] = (float)(1.0 / ssum);
    }
    __syncthreads();
    for (int i = tid; i < 64 * 80; i += 256) {
        int r = i / 80;
        int c = i - r * 80;
        int gr = row0 + r;
        if (gr < nrows) {
            float v = buf[r * 81 + c + 1] * inv[r];
            scr[(size_t)gr * 80 + c] = v;
            if (v > SCORE_THR) {
                int img = gr / A_TOTAL;
                atomicAdd(&hist[img * NBIN + (__float_as_uint(v) >> 16)], 1u);
            }
        }
    }
}

// ---------------------------------------------------------------------------
__global__ void zero_kernel(unsigned int* __restrict__ p, int n)
{
    int i = blockIdx.x * blockDim.x + threadIdx.x;
    if (i < n) p[i] = 0u;
}

// ---------------------------------------------------------------------------
// select: per-thread 64-bin partials + LDS suffix-scan (22 barriers vs 640).
// b0 = first bin (from top) where cumulative count reaches KCAND; 0 if never.
// ---------------------------------------------------------------------------
__global__ __launch_bounds__(1024) void select_kernel(
    const unsigned int* __restrict__ hist, unsigned int* __restrict__ sel)
{
    __shared__ unsigned int ps[1024];
    __shared__ int s_found;
    const int img = blockIdx.x;
    const int tid = threadIdx.x;

    unsigned int p = 0;
    const int base = img * NBIN + tid * 64;
    for (int j = 0; j < 64; j++) p += hist[base + j];
    ps[tid] = p;
    if (tid == 0) s_found = 0;
    __syncthreads();

    // inclusive suffix sum: ps[t] = sum_{t' >= t} p[t']
    for (int off = 1; off < 1024; off <<= 1) {
        unsigned int v = (tid + off < 1024) ? ps[tid + off] : 0u;
        __syncthreads();
        ps[tid] += v;
        __syncthreads();
    }

    unsigned int St = ps[tid];
    unsigned int Sn = (tid < 1023) ? ps[tid + 1] : 0u;
    if (St >= KCAND && (tid == 1023 || Sn < KCAND)) {
        // unique thread: walk its 64 bins from the top
        unsigned int cum = Sn;
        int b0 = 0;
        for (int b = tid * 64 + 63; b >= tid * 64; b--) {
            cum += hist[img * NBIN + b];
            if (cum >= KCAND) { b0 = b; break; }
        }
        sel[img] = (unsigned int)b0;
        s_found = 1;
    }
    __syncthreads();
    if (tid == 0 && !s_found) sel[img] = 0u;
}

// ---------------------------------------------------------------------------
__global__ void gather_kernel(const float* __restrict__ scr,
                              const unsigned int* __restrict__ sel,
                              unsigned int* __restrict__ candcnt,
                              uint2* __restrict__ cand)
{
    const int per_img = A_TOTAL * NCLS;
    const size_t total = (size_t)NIMG * per_img;
    for (size_t i = (size_t)blockIdx.x * blockDim.x + threadIdx.x; i < total;
         i += (size_t)gridDim.x * blockDim.x) {
        float v = scr[i];
        if (v > SCORE_THR) {
            int img = (int)(i / per_img);
            unsigned int u = __float_as_uint(v);
            if ((u >> 16) >= sel[img]) {
                unsigned int pos = atomicAdd(&candcnt[img], 1u);
                if (pos < CAND_CAP) {
                    unsigned int ridx = (unsigned int)(i - (size_t)img * per_img);
                    cand[(size_t)img * CAND_CAP + pos] = make_uint2(u, ridx);
                }
            }
        }
    }
}

// ---------------------------------------------------------------------------
__global__ __launch_bounds__(1024) void nms_kernel(
    const uint2* __restrict__ cand, const unsigned int* __restrict__ candcnt,
    const float* __restrict__ reg_all, const float* __restrict__ priors,
    float* __restrict__ out)
{
    __shared__ unsigned long long key[CAND_CAP];
    __shared__ float s_sc[KCAND];
    __shared__ float s_bx[KCAND][4];
    __shared__ float s_ob[KCAND][4];
    __shared__ float s_ar[KCAND];
    __shared__ float s_cl[KCAND];
    __shared__ int s_keep[KCAND];
    __shared__ int s_fi[KOUT];

    const int img = blockIdx.x;
    const int tid = threadIdx.x;
    unsigned int craw = candcnt[img];
    const int cnt = (craw > CAND_CAP) ? CAND_CAP : (int)craw;

    for (int i = tid; i < CAND_CAP; i += 1024) {
        unsigned long long kv = 0ull;
        if (i < cnt) {
            uint2 e = cand[(size_t)img * CAND_CAP + i];
            kv = ((unsigned long long)e.x << 32) | (unsigned int)(~e.y);
        }
        key[i] = kv;
    }
    __syncthreads();

    for (int ksz = 2; ksz <= CAND_CAP; ksz <<= 1) {
        for (int jj = ksz >> 1; jj > 0; jj >>= 1) {
            for (int i = tid; i < CAND_CAP; i += 1024) {
                int p = i ^ jj;
                if (p > i) {
                    bool desc = ((i & ksz) == 0);
                    unsigned long long a = key[i];
                    unsigned long long b = key[p];
                    bool sw = desc ? (a < b) : (a > b);
                    if (sw) { key[i] = b; key[p] = a; }
                }
            }
            __syncthreads();
        }
    }

    const float CLIPF = 4.135166556742356f;
    if (tid < KCAND) {
        const int j = tid;
        float s = 0.0f;
        unsigned int idx = 0u;
        if (j < cnt) {
            unsigned long long kv = key[j];
            unsigned int bits = (unsigned int)(kv >> 32);
            idx = ~((unsigned int)kv);
            s = __uint_as_float(bits);
        }
        int anc = (int)(idx / NCLS);
        int cl = (int)(idx - (unsigned int)anc * NCLS) + 1;
        const float* d = reg_all + ((size_t)img * A_TOTAL + anc) * 4;
        const float* pr = priors + (size_t)anc * 4;
        float d0 = d[0], d1 = d[1], d2 = d[2], d3 = d[3];
        float p0 = pr[0], p1 = pr[1], p2 = pr[2], p3 = pr[3];
        float cx = p0 + d0 * 0.1f * p2;
        float cy = p1 + d1 * 0.1f * p3;
        float t2 = fminf(d2 * 0.2f, CLIPF);
        float t3 = fminf(d3 * 0.2f, CLIPF);
        float bw = p2 * (float)exp((double)t2);
        float bh = p3 * (float)exp((double)t3);
        float x1 = clampf(cx - 0.5f * bw, 0.0f, CANVASF);
        float y1 = clampf(cy - 0.5f * bh, 0.0f, CANVASF);
        float x2 = clampf(cx + 0.5f * bw, 0.0f, CANVASF);
        float y2 = clampf(cy + 0.5f * bh, 0.0f, CANVASF);
        bool valid = (s > 0.0f) && (x2 > x1) && (y2 > y1);
        s = valid ? s : 0.0f;
        float off = (float)cl * (CANVASF + 1.0f);
        float ox1 = x1 + off, oy1 = y1 + off, ox2 = x2 + off, oy2 = y2 + off;
        s_sc[j] = s;
        s_cl[j] = (float)cl;
        s_keep[j] = valid ? 1 : 0;
        s_bx[j][0] = x1; s_bx[j][1] = y1; s_bx[j][2] = x2; s_bx[j][3] = y2;
        s_ob[j][0] = ox1; s_ob[j][1] = oy1; s_ob[j][2] = ox2; s_ob[j][3] = oy2;
        s_ar[j] = (ox2 - ox1) * (oy2 - oy1);
    }
    __syncthreads();

    for (int i = 0; i < KCAND; i++) {
        int ki = s_keep[i];
        if (ki && tid < KCAND && tid > i) {
            float lx = fmaxf(s_ob[i][0], s_ob[tid][0]);
            float ly = fmaxf(s_ob[i][1], s_ob[tid][1]);
            float rx = fminf(s_ob[i][2], s_ob[tid][2]);
            float ry = fminf(s_ob[i][3], s_ob[tid][3]);
            float iw = fmaxf(rx - lx, 0.0f);
            float ih = fmaxf(ry - ly, 0.0f);
            float inter = iw * ih;
            float iou = inter / (s_ar[i] + s_ar[tid] - inter + 1e-9f);
            if (iou > IOU_THRF) s_keep[tid] = 0;
        }
        __syncthreads();
    }

    if (tid == 0) {
        int pos = 0;
        for (int j = 0; j < KCAND && pos < KOUT; j++)
            if (s_keep[j]) s_fi[pos++] = j;
        for (int j = 0; j < KCAND && pos < KOUT; j++)
            if (!s_keep[j]) s_fi[pos++] = j;
    }
    __syncthreads();

    if (tid < KOUT) {
        int j = s_fi[tid];
        float fs = s_keep[j] ? s_sc[j] : 0.0f;
        size_t o = (size_t)img * KOUT + tid;
        out[o * 4 + 0] = s_bx[j][0];
        out[o * 4 + 1] = s_bx[j][1];
        out[o * 4 + 2] = s_bx[j][2];
        out[o * 4 + 3] = s_bx[j][3];
        out[(size_t)NIMG * KOUT * 4 + o] = fs;
        out[(size_t)NIMG * KOUT * 5 + o] = (fs > 0.0f) ? s_cl[j] : 0.0f;
    }
}

// ---------------------------------------------------------------------------
extern "C" void kernel_launch(void* const* d_in, const int* in_sizes, int n_in,
                              void* d_out, int out_size, void* d_ws, size_t ws_size,
                              hipStream_t stream)
{
    static const int Cin_[6] = {512, 1024, 512, 256, 256, 256};
    static const int lgC_[6] = {9, 10, 9, 8, 8, 8};
    static const int HW_[6]  = {38, 19, 10, 5, 3, 1};
    static const int an_[6]  = {4, 6, 6, 6, 4, 4};
    static const int off_[6] = {0, 5776, 7942, 8542, 8692, 8728};
    // combined (cls 81 + reg 4) transposed weights: M = an*85, Mp mult of 32
    static const int Mp_[6]  = {352, 512, 512, 512, 352, 352};
    // float offsets inside scr region (L4 goes to hist region instead)
    static const size_t wOffF_[6] = {0, 1622016, 6340608, 8699904, 0, 9879552};

    char* ws = (char*)d_ws;
    const size_t OFF_CLS  = 0;
    const size_t OFF_SCR  = 45266688;
    const size_t OFF_REG  = 89974528;
    const size_t OFF_HIST = 92209920;
    const size_t OFF_CCNT = 96404224;
    const size_t OFF_SEL  = 96404288;
    const size_t OFF_CAND = 96404352;

    float* cls_all = (float*)(ws + OFF_CLS);
    float* scr     = (float*)(ws + OFF_SCR);
    float* reg_all = (float*)(ws + OFF_REG);
    unsigned int* hist    = (unsigned int*)(ws + OFF_HIST);
    unsigned int* candcnt = (unsigned int*)(ws + OFF_CCNT);
    unsigned int* sel     = (unsigned int*)(ws + OFF_SEL);
    uint2* cand           = (uint2*)(ws + OFF_CAND);

    float* wT = scr;             // 42.8 MB of 44.7 MB scr region (L0-3, L5)
    float* hT = (float*)hist;    // 3.24 MB of 4.19 MB hist region (L4)

    // ---- combined weight transpose (cls + reg rows), before conv ----
    {
        TransJobs tj;
        int ts = 0;
        for (int L = 0; L < 6; L++) {
            tj.srcC[L] = (const float*)d_in[L * 5 + 1];
            tj.srcR[L] = (const float*)d_in[L * 5 + 3];
            tj.dst[L] = (L == 4) ? hT : (wT + wOffF_[L]);
            tj.Cin[L] = Cin_[L];
            tj.K[L] = Cin_[L] * 9;
            tj.Mcls[L] = an_[L] * TL_CLS;
            tj.Mtot[L] = an_[L] * 85;
            tj.Mp[L] = Mp_[L];
            tj.mT[L] = Mp_[L] / 32;
            tj.start[L] = ts;
            ts += (Mp_[L] / 32) * (Cin_[L] * 9 / 32);
        }
        tj.total = ts;
        transpose_wgt<<<ts, 256, 0, stream>>>(tj);
    }

    // ---- fused conv: XCD-chunked m-fastest wave tiles, CN=4 everywhere ----
    ConvJobs jobs;
    static const int ord_lvl[6] = {1, 0, 2, 3, 4, 5};
    int Bj[6];
    for (int q = 0; q < 6; q++) {
        int L = ord_lvl[q];
        int an = an_[L];
        jobs.feat[q]  = (const float*)d_in[L * 5 + 0];
        jobs.wgtT[q]  = (L == 4) ? hT : (wT + wOffF_[L]);
        jobs.biasC[q] = (const float*)d_in[L * 5 + 2];
        jobs.biasR[q] = (const float*)d_in[L * 5 + 4];
        jobs.Cin[q]   = Cin_[L];
        jobs.lgC[q]   = lgC_[L];
        jobs.Hd[q]    = HW_[L];
        jobs.Mcls[q]  = an * TL_CLS;
        jobs.Mtot[q]  = an * 85;
        jobs.Mp[q]    = Mp_[L];
        jobs.an[q]    = an;
        jobs.off[q]   = off_[L];
        int N = NIMG * HW_[L] * HW_[L];
        int nT = (N + 63) / 64;
        int mW = (jobs.Mtot[q] + 31) / 32;
        jobs.mW[q] = mW;
        jobs.jobTiles[q] = nT * mW;
        Bj[q] = (nT * mW + 3) / 4;
    }
    int maxT = 0;
    for (int x = 0; x < 8; x++) {
        int acc = 0;
        for (int q = 0; q < 6; q++) {
            int s = (int)(((long long)x * Bj[q]) / 8);
            int e = (int)(((long long)(x + 1) * Bj[q]) / 8);
            jobs.cs[x][q] = s;
            jobs.cum[x][q] = acc;
            acc += e - s;
        }
        jobs.cum[x][6] = acc;
        if (acc > maxT) maxT = acc;
    }
    jobs.outc = cls_all;
    jobs.outr = reg_all;

    fused_conv<<<8 * maxT, 256, 0, stream>>>(jobs);

    // zero hist/candcnt/sel AFTER conv (L4 weights live in the hist region)
    {
        int nz = NIMG * NBIN + 16 + 16;
        zero_kernel<<<(nz + 255) / 256, 256, 0, stream>>>(hist, nz);
    }

    softmax_kernel<<<(NIMG * A_TOTAL + 63) / 64, 256, 0, stream>>>(
        cls_all, scr, hist, NIMG * A_TOTAL);
    select_kernel<<<NIMG, 1024, 0, stream>>>(hist, sel);
    gather_kernel<<<2048, 256, 0, stream>>>(scr, sel, candcnt, cand);
    nms_kernel<<<NIMG, 1024, 0, stream>>>(cand, candcnt, reg_all,
                                          (const float*)d_in[30], (float*)d_out);
}